// Round 1
// 3770.808 us; speedup vs baseline: 1.1897x; 1.1897x over previous
//
#include <hip/hip_runtime.h>

#define B_ 64
#define C_ 128
#define H_ 36
#define W_ 100
#define K_ 9
#define PAD_ 4
#define NCHUNK 36            // K-dim = C_*K_ = 1152 = 36 chunks of 32
#define LDSTRIDE 152         // row stride in u16: 304 B -> 16B-aligned rows, 12-bank shift/row
#define BLROWS 120
#define PASSSZ (8 * NCHUNK * 64 * 8)   // u16 elems of swizzled weights per pass

typedef __attribute__((ext_vector_type(8))) short short8;
typedef __attribute__((ext_vector_type(4))) float f32x4;
typedef unsigned short u16;

__device__ __forceinline__ u16 f2bf(float f) {
    union { float f; unsigned u; } v; v.f = f;
    unsigned u = v.u;
    return (u16)((u + 0x7fffu + ((u >> 16) & 1u)) >> 16);
}

// Pre-swizzle weights into MFMA A-fragment order (bf16), K-order (kw outer, ci inner)
__global__ void prep_kernel(const float* __restrict__ wd, const float* __restrict__ wu,
                            const float* __restrict__ wr, const float* __restrict__ wl,
                            u16* __restrict__ afrag) {
    const int bid = blockIdx.x;             // p*288 + ct*36 + kk
    const int p = bid / (8 * NCHUNK);
    const int rem = bid % (8 * NCHUNK);
    const int ct = rem / NCHUNK;
    const int kk = rem % NCHUNK;
    const float* w = (p == 0) ? wd : (p == 1) ? wu : (p == 2) ? wr : wl;
    const int lane = threadIdx.x;
    const int co = ct * 16 + (lane & 15);
    const int k0 = kk * 32 + ((lane >> 4) << 3);
    u16 v[8];
#pragma unroll
    for (int j = 0; j < 8; ++j) {
        const int k = k0 + j;
        const int kw = k >> 7;
        const int ci = k & 127;
        v[j] = f2bf(w[(co * C_ + ci) * K_ + kw]);
    }
    u16* dst = afrag + ((size_t)(bid * 64 + lane)) * 8;
#pragma unroll
    for (int j = 0; j < 8; ++j) dst[j] = v[j];
}

// One block owns the whole batch: no inter-block sync, recurrence lives in LDS.
// 4 waves; wave w computes co-tiles {2w, 2w+1} (channels 32w..32w+31) for ALL l.
// Each B-fragment read from LDS feeds 2 MFMAs (2 co-tiles) -> LDS traffic halved.
template <int AXIS>
__device__ __forceinline__ void run_pass(
    const float* __restrict__ stbase,      // source for initial carry staging
    const float* __restrict__ sread,       // per-step skip-connection source
    float* __restrict__ fb,                // field (output), fp32
    const u16* __restrict__ afr,           // this pass's swizzled weights
    const float* __restrict__ bias,
    const int nsteps, const int start, const int dir, const int stage_t,
    u16 (*rowT)[BLROWS][LDSTRIDE])
{
    constexpr int L = (AXIS == 0) ? W_ : H_;
    constexpr int NLT = (AXIS == 0) ? 7 : 3;   // l-tiles of 16 (112>=100, 48>=36)
    const int tid = threadIdx.x;
    const int lane = tid & 63;
    const int wv = tid >> 6;               // 0..3
    const int q = lane >> 4, r = lane & 15;
    const int ct0 = 2 * wv, ct1 = ct0 + 1;
    const int cob0 = ct0 * 16 + (q << 2);
    const int cob1 = ct1 * 16 + (q << 2);

    // ---- weights for this wave's 2 co-tiles: register-resident (288 VGPRs) ----
    short8 areg0[NCHUNK], areg1[NCHUNK];
    {
        const u16* ap0 = afr + ((size_t)(ct0 * NCHUNK) * 64 + lane) * 8;
        const u16* ap1 = afr + ((size_t)(ct1 * NCHUNK) * 64 + lane) * 8;
#pragma unroll
        for (int kk = 0; kk < NCHUNK; ++kk) {
            areg0[kk] = *(const short8*)(ap0 + (size_t)kk * 512);
            areg1[kk] = *(const short8*)(ap1 + (size_t)kk * 512);
        }
    }
    float bias0[4], bias1[4];
#pragma unroll
    for (int j = 0; j < 4; ++j) { bias0[j] = bias[cob0 + j]; bias1[j] = bias[cob1 + j]; }

    // ---- stage initial carry row (full 128 ch) into buffer 0 ----
    for (int e = tid; e < C_ * L; e += 256) {
        const int c = e / L, l = e - c * L;
        const int fi = (AXIS == 0) ? (c * H_ + stage_t) * W_ + l
                                   : (c * H_ + l) * W_ + stage_t;
        rowT[0][l + PAD_][c] = f2bf(stbase[fi]);
    }
    __syncthreads();

    for (int s = 1; s <= nsteps; ++s) {
        const int cur = (s - 1) & 1, nxt = s & 1;
        const int t = start + dir * s;

#pragma unroll
        for (int ltp = 0; ltp < NLT; ltp += 2) {
            const bool two = (ltp + 1 < NLT);  // compile-time after unroll
            const int lA = ltp * 16 + r;
            const int lB = lA + 16;
            const bool vA = (lA < L);
            const bool vB = two && (lB < L);

            // prefetch skip-connection values; latency hides under the MFMA loop
            float svA0[4], svA1[4], svB0[4], svB1[4];
#pragma unroll
            for (int j = 0; j < 4; ++j) {
                const int fA0 = (AXIS == 0) ? ((cob0 + j) * H_ + t) * W_ + lA
                                            : ((cob0 + j) * H_ + lA) * W_ + t;
                const int fA1 = (AXIS == 0) ? ((cob1 + j) * H_ + t) * W_ + lA
                                            : ((cob1 + j) * H_ + lA) * W_ + t;
                svA0[j] = vA ? sread[fA0] : 0.0f;
                svA1[j] = vA ? sread[fA1] : 0.0f;
                if (two) {
                    const int fB0 = (AXIS == 0) ? ((cob0 + j) * H_ + t) * W_ + lB
                                                : ((cob0 + j) * H_ + lB) * W_ + t;
                    const int fB1 = (AXIS == 0) ? ((cob1 + j) * H_ + t) * W_ + lB
                                                : ((cob1 + j) * H_ + lB) * W_ + t;
                    svB0[j] = vB ? sread[fB0] : 0.0f;
                    svB1[j] = vB ? sread[fB1] : 0.0f;
                }
            }

            // 4 independent accumulator chains (2 co-tiles x 2 l-tiles) for MFMA ILP
            f32x4 aA0 = {0.f, 0.f, 0.f, 0.f};
            f32x4 aA1 = {0.f, 0.f, 0.f, 0.f};
            f32x4 aB0 = {0.f, 0.f, 0.f, 0.f};
            f32x4 aB1 = {0.f, 0.f, 0.f, 0.f};
#pragma unroll
            for (int kk = 0; kk < NCHUNK; ++kk) {
                const int kw = kk >> 2;
                const int cib = ((kk & 3) << 5) | (q << 3);
                const short8 bvA = *(const short8*)&rowT[cur][lA + kw][cib];
                aA0 = __builtin_amdgcn_mfma_f32_16x16x32_bf16(areg0[kk], bvA, aA0, 0, 0, 0);
                aA1 = __builtin_amdgcn_mfma_f32_16x16x32_bf16(areg1[kk], bvA, aA1, 0, 0, 0);
                if (two) {
                    const short8 bvB = *(const short8*)&rowT[cur][lB + kw][cib];
                    aB0 = __builtin_amdgcn_mfma_f32_16x16x32_bf16(areg0[kk], bvB, aB0, 0, 0, 0);
                    aB1 = __builtin_amdgcn_mfma_f32_16x16x32_bf16(areg1[kk], bvB, aB1, 0, 0, 0);
                }
            }

            auto epi = [&](int l, bool valid, const f32x4& a, const float* sv,
                           const int cob, const float* br) {
                if (!valid) return;
                union { u16 s4[4]; unsigned long long v; } pk;
#pragma unroll
                for (int j = 0; j < 4; ++j) {
                    const float conv = fmaxf(a[j] + br[j], 0.0f);
                    const int fi = (AXIS == 0) ? ((cob + j) * H_ + t) * W_ + l
                                               : ((cob + j) * H_ + l) * W_ + t;
                    const float nv = sv[j] + conv;
                    fb[fi] = nv;                       // fp32 field (fire & forget)
                    pk.s4[j] = f2bf(nv);
                }
                // next-step conv input, bf16, straight into the other LDS buffer
                *(unsigned long long*)&rowT[nxt][l + PAD_][cob] = pk.v;
            };
            epi(lA, vA, aA0, svA0, cob0, bias0);
            epi(lA, vA, aA1, svA1, cob1, bias1);
            if (two) {
                epi(lB, vB, aB0, svB0, cob0, bias0);
                epi(lB, vB, aB1, svB1, cob1, bias1);
            }
        }
        __syncthreads();   // single barrier per step: nxt fully written, cur free
    }
}

__global__ __launch_bounds__(256, 1) void spatial_kernel(
    const float* __restrict__ x, float* __restrict__ field,
    const u16* __restrict__ afrag,
    const float* __restrict__ bd, const float* __restrict__ bu,
    const float* __restrict__ br, const float* __restrict__ bl) {
    __shared__ __align__(16) u16 rowT[2][BLROWS][LDSTRIDE];
    const int b = blockIdx.x;              // one block per batch; no siblings
    const int tid = threadIdx.x;
    const float* xb = x + (size_t)b * C_ * H_ * W_;
    float* fb = field + (size_t)b * C_ * H_ * W_;

    // field row h=0 (= x); needed as skip/stage source by later passes
    for (int e = tid; e < C_ * W_; e += 256) {
        const int c = e / W_, w = e - c * W_;
        fb[(c * H_) * W_ + w] = xb[(c * H_) * W_ + w];
    }
    // zero LDS (halo rows must be 0)
    {
        u16* pz = &rowT[0][0][0];
        for (int off = tid * 8; off < 2 * BLROWS * LDSTRIDE; off += 256 * 8)
            *(uint4*)(pz + off) = make_uint4(0u, 0u, 0u, 0u);
    }
    __syncthreads();

    // down: h = 1..35 (stage from x row 0; skip source = x)
    run_pass<0>(xb, xb, fb, afrag + (size_t)0 * PASSSZ, bd, 35, 0, +1, 0, rowT);
    // up: h = 34..1 (stage from field row 35)
    run_pass<0>(fb, fb, fb, afrag + (size_t)1 * PASSSZ, bu, 34, 35, -1, 35, rowT);

    // re-zero LDS (H-pass left nonzero rows beyond W-pass halo)
    __syncthreads();
    {
        u16* pz = &rowT[0][0][0];
        for (int off = tid * 8; off < 2 * BLROWS * LDSTRIDE; off += 256 * 8)
            *(uint4*)(pz + off) = make_uint4(0u, 0u, 0u, 0u);
    }
    __syncthreads();

    // right: w = 1..99
    run_pass<1>(fb, fb, fb, afrag + (size_t)2 * PASSSZ, br, 99, 0, +1, 0, rowT);
    // left: w = 98..1
    run_pass<1>(fb, fb, fb, afrag + (size_t)3 * PASSSZ, bl, 98, 99, -1, 99, rowT);
}

extern "C" void kernel_launch(void* const* d_in, const int* in_sizes, int n_in,
                              void* d_out, int out_size, void* d_ws, size_t ws_size,
                              hipStream_t stream) {
    const float* x  = (const float*)d_in[0];
    const float* wd = (const float*)d_in[1];
    const float* bd = (const float*)d_in[2];
    const float* wu = (const float*)d_in[3];
    const float* bu = (const float*)d_in[4];
    const float* wr = (const float*)d_in[5];
    const float* br = (const float*)d_in[6];
    const float* wl = (const float*)d_in[7];
    const float* bl = (const float*)d_in[8];

    // ws layout: [0,1KB) reserved | [1KB, +1.18MB) afrag
    u16* afrag = (u16*)((char*)d_ws + 1024);

    prep_kernel<<<dim3(4 * 8 * NCHUNK), dim3(64), 0, stream>>>(wd, wu, wr, wl, afrag);
    spatial_kernel<<<dim3(64), dim3(256), 0, stream>>>(
        x, (float*)d_out, afrag, bd, bu, br, bl);
}

// Round 2
// 2706.869 us; speedup vs baseline: 1.6574x; 1.3931x over previous
//
#include <hip/hip_runtime.h>

#define B_ 64
#define C_ 128
#define H_ 36
#define W_ 100
#define K_ 9
#define PAD_ 4
#define NCHUNK 36            // K-dim = C_*K_ = 1152 = 36 chunks of 32
#define LDSTRIDE 152         // row stride in u16: 304 B -> 16B-aligned rows, 12-bank shift/row
#define BLROWS 120
#define PASSSZ (8 * NCHUNK * 64 * 8)   // u16 elems of swizzled weights per pass

typedef __attribute__((ext_vector_type(8))) short short8;
typedef __attribute__((ext_vector_type(4))) float f32x4;
typedef unsigned short u16;

__device__ __forceinline__ u16 f2bf(float f) {
    union { float f; unsigned u; } v; v.f = f;
    unsigned u = v.u;
    return (u16)((u + 0x7fffu + ((u >> 16) & 1u)) >> 16);
}

// Pre-swizzle weights into MFMA A-fragment order (bf16), K-order (kw outer, ci inner)
__global__ void prep_kernel(const float* __restrict__ wd, const float* __restrict__ wu,
                            const float* __restrict__ wr, const float* __restrict__ wl,
                            u16* __restrict__ afrag) {
    const int bid = blockIdx.x;             // p*288 + ct*36 + kk
    const int p = bid / (8 * NCHUNK);
    const int rem = bid % (8 * NCHUNK);
    const int ct = rem / NCHUNK;
    const int kk = rem % NCHUNK;
    const float* w = (p == 0) ? wd : (p == 1) ? wu : (p == 2) ? wr : wl;
    const int lane = threadIdx.x;
    const int co = ct * 16 + (lane & 15);
    const int k0 = kk * 32 + ((lane >> 4) << 3);
    u16 v[8];
#pragma unroll
    for (int j = 0; j < 8; ++j) {
        const int k = k0 + j;
        const int kw = k >> 7;
        const int ci = k & 127;
        v[j] = f2bf(w[(co * C_ + ci) * K_ + kw]);
    }
    u16* dst = afrag + ((size_t)(bid * 64 + lane)) * 8;
#pragma unroll
    for (int j = 0; j < 8; ++j) dst[j] = v[j];
}

// Within-pass step barrier: drain own LDS ops only; global stores stay in flight
// (all within-pass global RAW pairs are same-thread, data-dep ordered).
__device__ __forceinline__ void step_barrier() {
    asm volatile("s_waitcnt lgkmcnt(0)\n\ts_barrier" ::: "memory");
}

// One block owns the whole batch. 4 waves; wave w computes co-tiles {2w, 2w+1}
// (channels 32w..32w+31) for ALL l. Each LDS B-fragment read feeds 2 MFMAs.
// Weight residency: areg1 fully + areg0[18..35] pinned to AGPRs (216 AGPR),
// leaving ~160 arch VGPRs -> no scratch spill (the round-1 killer).
template <int AXIS>
__device__ __forceinline__ void run_pass(
    const float* __restrict__ stbase,      // source for initial carry staging
    const float* __restrict__ sread,       // per-step skip-connection source
    float* __restrict__ fb,                // field (output), fp32
    const u16* __restrict__ afr,           // this pass's swizzled weights
    const float* __restrict__ bias,
    const int nsteps, const int start, const int dir, const int stage_t,
    u16 (*rowT)[BLROWS][LDSTRIDE])
{
    constexpr int L = (AXIS == 0) ? W_ : H_;
    constexpr int NLT = (AXIS == 0) ? 7 : 3;   // l-tiles of 16 (112>=100, 48>=36)
    const int tid = threadIdx.x;
    const int lane = tid & 63;
    const int wv = tid >> 6;               // 0..3
    const int q = lane >> 4, r = lane & 15;
    const int ct0 = 2 * wv, ct1 = ct0 + 1;
    const int cob0 = ct0 * 16 + (q << 2);
    const int cob1 = ct1 * 16 + (q << 2);

    // ---- weights for this wave's 2 co-tiles; force AGPR residency ----
    short8 areg0[NCHUNK], areg1[NCHUNK];
    {
        const u16* ap0 = afr + ((size_t)(ct0 * NCHUNK) * 64 + lane) * 8;
        const u16* ap1 = afr + ((size_t)(ct1 * NCHUNK) * 64 + lane) * 8;
#pragma unroll
        for (int kk = 0; kk < NCHUNK; ++kk) {
            areg0[kk] = *(const short8*)(ap0 + (size_t)kk * 512);
            areg1[kk] = *(const short8*)(ap1 + (size_t)kk * 512);
            asm("" : "+a"(areg1[kk]));           // pin to AGPR (36 x 4 = 144 AGPR)
            if (kk >= 18) asm("" : "+a"(areg0[kk]));  // 18 x 4 = 72 AGPR
        }
    }
    float bias0[4], bias1[4];
#pragma unroll
    for (int j = 0; j < 4; ++j) { bias0[j] = bias[cob0 + j]; bias1[j] = bias[cob1 + j]; }

    // entry: full barrier drains previous pass's global writes (cross-thread reads
    // below: staging + this pass's skip-prefetches of other passes' outputs)
    __syncthreads();

    // ---- stage initial carry row (full 128 ch) into buffer 0 ----
    for (int e = tid; e < C_ * L; e += 256) {
        const int c = e / L, l = e - c * L;
        const int fi = (AXIS == 0) ? (c * H_ + stage_t) * W_ + l
                                   : (c * H_ + l) * W_ + stage_t;
        rowT[0][l + PAD_][c] = f2bf(stbase[fi]);
    }
    __syncthreads();

    for (int s = 1; s <= nsteps; ++s) {
        const int cur = (s - 1) & 1, nxt = s & 1;
        const int t = start + dir * s;

#pragma unroll
        for (int ltp = 0; ltp < NLT; ltp += 2) {
            const bool two = (ltp + 1 < NLT);  // compile-time after unroll
            const int lA = ltp * 16 + r;
            const int lB = lA + 16;
            const bool vA = (lA < L);
            const bool vB = two && (lB < L);

            // prefetch skip-connection values; latency hides under the MFMA loop
            float svA0[4], svA1[4], svB0[4], svB1[4];
#pragma unroll
            for (int j = 0; j < 4; ++j) {
                const int fA0 = (AXIS == 0) ? ((cob0 + j) * H_ + t) * W_ + lA
                                            : ((cob0 + j) * H_ + lA) * W_ + t;
                const int fA1 = (AXIS == 0) ? ((cob1 + j) * H_ + t) * W_ + lA
                                            : ((cob1 + j) * H_ + lA) * W_ + t;
                svA0[j] = vA ? sread[fA0] : 0.0f;
                svA1[j] = vA ? sread[fA1] : 0.0f;
                if (two) {
                    const int fB0 = (AXIS == 0) ? ((cob0 + j) * H_ + t) * W_ + lB
                                                : ((cob0 + j) * H_ + lB) * W_ + t;
                    const int fB1 = (AXIS == 0) ? ((cob1 + j) * H_ + t) * W_ + lB
                                                : ((cob1 + j) * H_ + lB) * W_ + t;
                    svB0[j] = vB ? sread[fB0] : 0.0f;
                    svB1[j] = vB ? sread[fB1] : 0.0f;
                }
            }

            // 4 independent accumulator chains; bias folded into C-init
            f32x4 aA0 = {bias0[0], bias0[1], bias0[2], bias0[3]};
            f32x4 aA1 = {bias1[0], bias1[1], bias1[2], bias1[3]};
            f32x4 aB0 = aA0;
            f32x4 aB1 = aA1;
#pragma unroll
            for (int kk = 0; kk < NCHUNK; ++kk) {
                const int kw = kk >> 2;
                const int cib = ((kk & 3) << 5) | (q << 3);
                const short8 bvA = *(const short8*)&rowT[cur][lA + kw][cib];
                aA0 = __builtin_amdgcn_mfma_f32_16x16x32_bf16(areg0[kk], bvA, aA0, 0, 0, 0);
                aA1 = __builtin_amdgcn_mfma_f32_16x16x32_bf16(areg1[kk], bvA, aA1, 0, 0, 0);
                if (two) {
                    const short8 bvB = *(const short8*)&rowT[cur][lB + kw][cib];
                    aB0 = __builtin_amdgcn_mfma_f32_16x16x32_bf16(areg0[kk], bvB, aB0, 0, 0, 0);
                    aB1 = __builtin_amdgcn_mfma_f32_16x16x32_bf16(areg1[kk], bvB, aB1, 0, 0, 0);
                }
            }

            auto epi = [&](int l, bool valid, const f32x4& a, const float* sv,
                           const int cob) {
                if (!valid) return;
                union { u16 s4[4]; unsigned long long v; } pk;
#pragma unroll
                for (int j = 0; j < 4; ++j) {
                    const float conv = fmaxf(a[j], 0.0f);   // bias already in acc
                    const int fi = (AXIS == 0) ? ((cob + j) * H_ + t) * W_ + l
                                               : ((cob + j) * H_ + l) * W_ + t;
                    const float nv = sv[j] + conv;
                    fb[fi] = nv;                       // fp32 field (fire & forget)
                    pk.s4[j] = f2bf(nv);
                }
                // next-step conv input, bf16, straight into the other LDS buffer
                *(unsigned long long*)&rowT[nxt][l + PAD_][cob] = pk.v;
            };
            epi(lA, vA, aA0, svA0, cob0);
            epi(lA, vA, aA1, svA1, cob1);
            if (two) {
                epi(lB, vB, aB0, svB0, cob0);
                epi(lB, vB, aB1, svB1, cob1);
            }
        }
        step_barrier();   // LDS-only drain; global stores keep flying
    }
}

__global__ __launch_bounds__(256, 1) void spatial_kernel(
    const float* __restrict__ x, float* __restrict__ field,
    const u16* __restrict__ afrag,
    const float* __restrict__ bd, const float* __restrict__ bu,
    const float* __restrict__ br, const float* __restrict__ bl) {
    __shared__ __align__(16) u16 rowT[2][BLROWS][LDSTRIDE];
    const int b = blockIdx.x;              // one block per batch; no siblings
    const int tid = threadIdx.x;
    const float* xb = x + (size_t)b * C_ * H_ * W_;
    float* fb = field + (size_t)b * C_ * H_ * W_;

    // field row h=0 (= x); needed as skip/stage source by later passes
    for (int e = tid; e < C_ * W_; e += 256) {
        const int c = e / W_, w = e - c * W_;
        fb[(c * H_) * W_ + w] = xb[(c * H_) * W_ + w];
    }
    // zero LDS (halo rows must be 0); ordered vs staging by run_pass entry sync
    {
        u16* pz = &rowT[0][0][0];
        for (int off = tid * 8; off < 2 * BLROWS * LDSTRIDE; off += 256 * 8)
            *(uint4*)(pz + off) = make_uint4(0u, 0u, 0u, 0u);
    }

    // down: h = 1..35 (stage from x row 0; skip source = x)
    run_pass<0>(xb, xb, fb, afrag + (size_t)0 * PASSSZ, bd, 35, 0, +1, 0, rowT);
    // up: h = 34..1 (stage from field row 35)
    run_pass<0>(fb, fb, fb, afrag + (size_t)1 * PASSSZ, bu, 34, 35, -1, 35, rowT);

    // re-zero LDS (H-pass left nonzero rows beyond W-pass halo); safe: up-pass's
    // final step_barrier drained all LDS ops; ordered vs staging by entry sync
    {
        u16* pz = &rowT[0][0][0];
        for (int off = tid * 8; off < 2 * BLROWS * LDSTRIDE; off += 256 * 8)
            *(uint4*)(pz + off) = make_uint4(0u, 0u, 0u, 0u);
    }

    // right: w = 1..99
    run_pass<1>(fb, fb, fb, afrag + (size_t)2 * PASSSZ, br, 99, 0, +1, 0, rowT);
    // left: w = 98..1
    run_pass<1>(fb, fb, fb, afrag + (size_t)3 * PASSSZ, bl, 98, 99, -1, 99, rowT);
}

extern "C" void kernel_launch(void* const* d_in, const int* in_sizes, int n_in,
                              void* d_out, int out_size, void* d_ws, size_t ws_size,
                              hipStream_t stream) {
    const float* x  = (const float*)d_in[0];
    const float* wd = (const float*)d_in[1];
    const float* bd = (const float*)d_in[2];
    const float* wu = (const float*)d_in[3];
    const float* bu = (const float*)d_in[4];
    const float* wr = (const float*)d_in[5];
    const float* br = (const float*)d_in[6];
    const float* wl = (const float*)d_in[7];
    const float* bl = (const float*)d_in[8];

    // ws layout: [0,1KB) reserved | [1KB, +1.18MB) afrag
    u16* afrag = (u16*)((char*)d_ws + 1024);

    prep_kernel<<<dim3(4 * 8 * NCHUNK), dim3(64), 0, stream>>>(wd, wu, wr, wl, afrag);
    spatial_kernel<<<dim3(64), dim3(256), 0, stream>>>(
        x, (float*)d_out, afrag, bd, bu, br, bl);
}

// Round 3
// 1852.051 us; speedup vs baseline: 2.4223x; 1.4616x over previous
//
#include <hip/hip_runtime.h>

#define B_ 64
#define C_ 128
#define H_ 36
#define W_ 100
#define K_ 9
#define PAD_ 4
#define NCHUNK 36            // K-dim = C_*K_ = 1152 = 36 chunks of 32
#define LDSTRIDE 152         // row stride in u16: 304 B -> 16B-aligned rows
#define NR_H 120             // LDS rows for H-pass buffers (reads reach 119)
#define NR_W 56              // LDS rows for W-pass buffers (reads reach 55)
#define PASSSZ (8 * NCHUNK * 64 * 8)   // u16 elems of swizzled weights per pass
#define FBT_ELEMS ((size_t)B_ * W_ * C_ * H_)
#define FBT_OFF ((size_t)4 << 20)

typedef __attribute__((ext_vector_type(8))) short short8;
typedef __attribute__((ext_vector_type(4))) float f32x4;
typedef unsigned short u16;

__device__ __forceinline__ u16 f2bf(float f) {
    union { float f; unsigned u; } v; v.f = f;
    unsigned u = v.u;
    return (u16)((u + 0x7fffu + ((u >> 16) & 1u)) >> 16);
}
__device__ __forceinline__ float bf2f(u16 h) {
    union { unsigned u; float f; } v; v.u = ((unsigned)h) << 16; return v.f;
}
__device__ __forceinline__ float lodv(const float* p) { return *p; }
__device__ __forceinline__ float lodv(const u16* p) { return bf2f(*p); }
__device__ __forceinline__ void storv(float* p, float v) { *p = v; }
__device__ __forceinline__ void storv(u16* p, float v) { *p = f2bf(v); }

// Pre-swizzle weights into MFMA A-fragment order (bf16), K-order (kw outer, ci inner)
__global__ void prep_kernel(const float* __restrict__ wd, const float* __restrict__ wu,
                            const float* __restrict__ wr, const float* __restrict__ wl,
                            u16* __restrict__ afrag) {
    const int bid = blockIdx.x;             // p*288 + ct*36 + kk
    const int p = bid / (8 * NCHUNK);
    const int rem = bid % (8 * NCHUNK);
    const int ct = rem / NCHUNK;
    const int kk = rem % NCHUNK;
    const float* w = (p == 0) ? wd : (p == 1) ? wu : (p == 2) ? wr : wl;
    const int lane = threadIdx.x;
    const int co = ct * 16 + (lane & 15);
    const int k0 = kk * 32 + ((lane >> 4) << 3);
    u16 v[8];
#pragma unroll
    for (int j = 0; j < 8; ++j) {
        const int k = k0 + j;
        const int kw = k >> 7;
        const int ci = k & 127;
        v[j] = f2bf(w[(co * C_ + ci) * K_ + kw]);
    }
    u16* dst = afrag + ((size_t)(bid * 64 + lane)) * 8;
#pragma unroll
    for (int j = 0; j < 8; ++j) dst[j] = v[j];
}

// Within-pass step barrier: drain own LDS ops only; global stores stay in flight
__device__ __forceinline__ void step_barrier() {
    asm volatile("s_waitcnt lgkmcnt(0)\n\ts_barrier" ::: "memory");
}

// 4 waves; wave w computes co-tiles {2w, 2w+1} for ALL l. Each LDS B-fragment
// read feeds 2 MFMAs. areg1 + areg0[18..35] pinned to AGPRs -> no scratch.
// SKIP_T / STORE_T select normal [c][h][w] vs column-major [t][c][h] layouts.
template <int AXIS, bool SKIP_T, bool STORE_T, int NROWS, typename TF>
__device__ __forceinline__ void run_pass(
    const float* __restrict__ stbase,      // initial-carry source (normal layout)
    const float* __restrict__ sread,       // skip source (normal layout)
    float* __restrict__ fb,                // normal-layout output (STORE_T=false)
    TF* __restrict__ fbT,                  // column-major field (W passes)
    const u16* __restrict__ afr,           // this pass's swizzled weights
    const float* __restrict__ bias,
    const int nsteps, const int start, const int dir, const int stage_t,
    u16* __restrict__ lds)
{
    constexpr int L = (AXIS == 0) ? W_ : H_;
    constexpr int NLT = (AXIS == 0) ? 7 : 3;   // l-tiles of 16
    const int tid = threadIdx.x;
    const int lane = tid & 63;
    const int wv = tid >> 6;               // 0..3
    const int q = lane >> 4, r = lane & 15;
    const int ct0 = 2 * wv, ct1 = ct0 + 1;
    const int cob0 = ct0 * 16 + (q << 2);
    const int cob1 = ct1 * 16 + (q << 2);

    // ---- weights for this wave's 2 co-tiles; force AGPR residency ----
    short8 areg0[NCHUNK], areg1[NCHUNK];
    {
        const u16* ap0 = afr + ((size_t)(ct0 * NCHUNK) * 64 + lane) * 8;
        const u16* ap1 = afr + ((size_t)(ct1 * NCHUNK) * 64 + lane) * 8;
#pragma unroll
        for (int kk = 0; kk < NCHUNK; ++kk) {
            areg0[kk] = *(const short8*)(ap0 + (size_t)kk * 512);
            areg1[kk] = *(const short8*)(ap1 + (size_t)kk * 512);
            asm("" : "+a"(areg1[kk]));
            if (kk >= 18) asm("" : "+a"(areg0[kk]));
        }
    }
    float bias0[4], bias1[4];
#pragma unroll
    for (int j = 0; j < 4; ++j) { bias0[j] = bias[cob0 + j]; bias1[j] = bias[cob1 + j]; }

    // entry: full barrier (drains prior pass's global writes for cross-thread reads)
    __syncthreads();

    // ---- stage initial carry (full 128 ch) into buffer 0 ----
    for (int e = tid; e < C_ * L; e += 256) {
        const int c = e / L, l = e - c * L;
        float fv;
        if constexpr (SKIP_T)
            fv = lodv(&fbT[((size_t)stage_t * C_ + c) * H_ + l]);
        else
            fv = stbase[(AXIS == 0) ? (c * H_ + stage_t) * W_ + l
                                    : (c * H_ + l) * W_ + stage_t];
        lds[(l + PAD_) * LDSTRIDE + c] = f2bf(fv);
        if constexpr (STORE_T && !SKIP_T)   // right pass: publish carry col to fbT
            storv(&fbT[((size_t)stage_t * C_ + c) * H_ + l], fv);
    }
    __syncthreads();

    for (int s = 1; s <= nsteps; ++s) {
        const int cur = (s - 1) & 1, nxt = s & 1;
        const int t = start + dir * s;
        const u16* curb = lds + (size_t)cur * NROWS * LDSTRIDE;
        u16* nxtb = lds + (size_t)nxt * NROWS * LDSTRIDE;

#pragma unroll
        for (int ltp = 0; ltp < NLT; ltp += 2) {
            const bool two = (ltp + 1 < NLT);
            const int lA = ltp * 16 + r;
            const int lB = lA + 16;
            const bool vA = (lA < L);
            const bool vB = two && (lB < L);

            auto ld_skip = [&](int co, int l) -> float {
                if constexpr (SKIP_T) {
                    return lodv(&fbT[((size_t)t * C_ + co) * H_ + l]);
                } else {
                    const int fi = (AXIS == 0) ? (co * H_ + t) * W_ + l
                                               : (co * H_ + l) * W_ + t;
                    return sread[fi];
                }
            };
            float svA0[4], svA1[4], svB0[4], svB1[4];
#pragma unroll
            for (int j = 0; j < 4; ++j) {
                svA0[j] = vA ? ld_skip(cob0 + j, lA) : 0.0f;
                svA1[j] = vA ? ld_skip(cob1 + j, lA) : 0.0f;
                if (two) {
                    svB0[j] = vB ? ld_skip(cob0 + j, lB) : 0.0f;
                    svB1[j] = vB ? ld_skip(cob1 + j, lB) : 0.0f;
                }
            }

            f32x4 aA0 = {bias0[0], bias0[1], bias0[2], bias0[3]};
            f32x4 aA1 = {bias1[0], bias1[1], bias1[2], bias1[3]};
            f32x4 aB0 = aA0;
            f32x4 aB1 = aA1;
#pragma unroll
            for (int kk = 0; kk < NCHUNK; ++kk) {
                const int kw = kk >> 2;
                const int cib = ((kk & 3) << 5) | (q << 3);
                const short8 bvA = *(const short8*)&curb[(lA + kw) * LDSTRIDE + cib];
                aA0 = __builtin_amdgcn_mfma_f32_16x16x32_bf16(areg0[kk], bvA, aA0, 0, 0, 0);
                aA1 = __builtin_amdgcn_mfma_f32_16x16x32_bf16(areg1[kk], bvA, aA1, 0, 0, 0);
                if (two) {
                    const short8 bvB = *(const short8*)&curb[(lB + kw) * LDSTRIDE + cib];
                    aB0 = __builtin_amdgcn_mfma_f32_16x16x32_bf16(areg0[kk], bvB, aB0, 0, 0, 0);
                    aB1 = __builtin_amdgcn_mfma_f32_16x16x32_bf16(areg1[kk], bvB, aB1, 0, 0, 0);
                }
            }

            auto epi = [&](int l, bool valid, const f32x4& a, const float* sv,
                           const int cob) {
                if (!valid) return;
                union { u16 s4[4]; unsigned long long v; } pk;
#pragma unroll
                for (int j = 0; j < 4; ++j) {
                    const float conv = fmaxf(a[j], 0.0f);   // bias already in acc
                    const float nv = sv[j] + conv;
                    if constexpr (STORE_T) {
                        storv(&fbT[((size_t)t * C_ + cob + j) * H_ + l], nv);
                    } else {
                        const int fi = (AXIS == 0) ? ((cob + j) * H_ + t) * W_ + l
                                                   : ((cob + j) * H_ + l) * W_ + t;
                        fb[fi] = nv;
                    }
                    pk.s4[j] = f2bf(nv);
                }
                *(unsigned long long*)&nxtb[(l + PAD_) * LDSTRIDE + cob] = pk.v;
            };
            epi(lA, vA, aA0, svA0, cob0);
            epi(lA, vA, aA1, svA1, cob1);
            if (two) {
                epi(lB, vB, aB0, svB0, cob0);
                epi(lB, vB, aB1, svB1, cob1);
            }
        }
        step_barrier();   // LDS-only drain; global stores keep flying
    }
}

__global__ __launch_bounds__(256, 1) void spatialH(
    const float* __restrict__ x, float* __restrict__ fb,
    const u16* __restrict__ afrag,
    const float* __restrict__ bd, const float* __restrict__ bu) {
    __shared__ __align__(16) u16 lds[2 * NR_H * LDSTRIDE];
    const int b = blockIdx.x;
    const int tid = threadIdx.x;
    const float* xb = x + (size_t)b * C_ * H_ * W_;
    float* fbb = fb + (size_t)b * C_ * H_ * W_;

    // field row h=0 (= x)
    for (int e = tid; e < C_ * W_; e += 256) {
        const int c = e / W_, w = e - c * W_;
        fbb[(c * H_) * W_ + w] = xb[(c * H_) * W_ + w];
    }
    // zero LDS (halo rows must be 0); ordered vs staging by run_pass entry sync
    for (int off = tid * 8; off < 2 * NR_H * LDSTRIDE; off += 256 * 8)
        *(uint4*)(&lds[off]) = make_uint4(0u, 0u, 0u, 0u);

    // down: h = 1..35 ; up: h = 34..1
    run_pass<0, false, false, NR_H, float>(xb, xb, fbb, (float*)nullptr,
        afrag + (size_t)0 * PASSSZ, bd, 35, 0, +1, 0, lds);
    run_pass<0, false, false, NR_H, float>(fbb, fbb, fbb, (float*)nullptr,
        afrag + (size_t)1 * PASSSZ, bu, 34, 35, -1, 35, lds);
}

template <typename TF>
__global__ __launch_bounds__(256, 1) void spatialW(
    const float* __restrict__ fbr, TF* __restrict__ fbT,
    const u16* __restrict__ afrag,
    const float* __restrict__ br_, const float* __restrict__ bl_) {
    __shared__ __align__(16) u16 lds[2 * NR_W * LDSTRIDE];
    const int b = blockIdx.x;
    const int tid = threadIdx.x;
    const float* fbb = fbr + (size_t)b * C_ * H_ * W_;
    TF* fbTb = fbT + (size_t)b * W_ * C_ * H_;

    for (int off = tid * 8; off < 2 * NR_W * LDSTRIDE; off += 256 * 8)
        *(uint4*)(&lds[off]) = make_uint4(0u, 0u, 0u, 0u);

    // right: w = 1..99 (skip+stage from normal field; stores dense to fbT)
    run_pass<1, false, true, NR_W, TF>(fbb, fbb, (float*)nullptr, fbTb,
        afrag + (size_t)2 * PASSSZ, br_, 99, 0, +1, 0, lds);
    // left: w = 98..1 (skip+stage+stores all dense on fbT, in-place)
    run_pass<1, true, true, NR_W, TF>((const float*)nullptr, (const float*)nullptr,
        (float*)nullptr, fbTb, afrag + (size_t)3 * PASSSZ, bl_, 98, 99, -1, 99, lds);
}

// fbT[b][w][c][h] -> out[b][c][h][w], LDS-tiled, both sides coalesced
template <typename TF>
__global__ void t2_kernel(const TF* __restrict__ fbT, float* __restrict__ out) {
    __shared__ float tile[16 * 36 * 17];
    const int tid = threadIdx.x;
    const int bid = blockIdx.x;            // b*56 + cs*7 + wc
    const int b = bid / 56;
    const int rem = bid % 56;
    const int cs = rem / 7, wc = rem % 7;
    const int w0 = wc * 16;
    const int wlen = (w0 + 16 <= W_) ? 16 : (W_ - w0);
    const int c0 = cs * 16;
    const TF* src = fbT + (size_t)b * W_ * C_ * H_;

    for (int i = tid; i < 576 * wlen; i += 256) {
        const int w = i / 576;
        const int ch = i - w * 576;
        const int c = ch / 36, h = ch - c * 36;
        tile[(c * 36 + h) * 17 + w] = lodv(&src[((size_t)(w0 + w) * C_ + c0 + c) * H_ + h]);
    }
    __syncthreads();
    for (int j = tid; j < 576 * 16; j += 256) {
        const int w = j & 15;
        const int ch = j >> 4;
        if (w >= wlen) continue;
        const int c = ch / 36, h = ch - c * 36;
        out[(((size_t)b * C_ + c0 + c) * H_ + h) * W_ + w0 + w] = tile[(c * 36 + h) * 17 + w];
    }
}

extern "C" void kernel_launch(void* const* d_in, const int* in_sizes, int n_in,
                              void* d_out, int out_size, void* d_ws, size_t ws_size,
                              hipStream_t stream) {
    const float* x  = (const float*)d_in[0];
    const float* wd = (const float*)d_in[1];
    const float* bd = (const float*)d_in[2];
    const float* wu = (const float*)d_in[3];
    const float* bu = (const float*)d_in[4];
    const float* wr = (const float*)d_in[5];
    const float* br = (const float*)d_in[6];
    const float* wl = (const float*)d_in[7];
    const float* bl = (const float*)d_in[8];

    // ws layout: [0,1KB) unused | afrag (2.36 MB) | pad | fbT @ 4MB (118/59 MB)
    u16* afrag = (u16*)((char*)d_ws + 1024);
    void* fbTp = (char*)d_ws + FBT_OFF;
    const bool f32ok = ws_size >= FBT_OFF + sizeof(float) * FBT_ELEMS;

    prep_kernel<<<dim3(4 * 8 * NCHUNK), dim3(64), 0, stream>>>(wd, wu, wr, wl, afrag);
    spatialH<<<dim3(64), dim3(256), 0, stream>>>(x, (float*)d_out, afrag, bd, bu);
    if (f32ok) {
        spatialW<float><<<dim3(64), dim3(256), 0, stream>>>(
            (const float*)d_out, (float*)fbTp, afrag, br, bl);
        t2_kernel<float><<<dim3(64 * 56), dim3(256), 0, stream>>>(
            (const float*)fbTp, (float*)d_out);
    } else {
        spatialW<u16><<<dim3(64), dim3(256), 0, stream>>>(
            (const float*)d_out, (u16*)fbTp, afrag, br, bl);
        t2_kernel<u16><<<dim3(64 * 56), dim3(256), 0, stream>>>(
            (const u16*)fbTp, (float*)d_out);
    }
}

// Round 4
// 1464.971 us; speedup vs baseline: 3.0624x; 1.2642x over previous
//
#include <hip/hip_runtime.h>

#define B_ 64
#define C_ 128
#define H_ 36
#define W_ 100
#define K_ 9
#define PAD_ 4
#define NCHUNK 36            // K-dim = C_*K_ = 1152 = 36 chunks of 32
#define LDSTRIDE 152         // row stride in u16: 304 B -> 16B-aligned rows
#define NR_H 120             // LDS rows for H-pass buffers (reads reach 119)
#define NR_W 56              // LDS rows for W-pass buffers (reads reach 55)
#define PASSSZ (8 * NCHUNK * 64 * 8)   // u16 elems of swizzled weights per pass
#define FBT_ELEMS ((size_t)B_ * W_ * C_ * H_)
#define FBT_OFF ((size_t)4 << 20)

typedef __attribute__((ext_vector_type(8))) short short8;
typedef __attribute__((ext_vector_type(4))) float f32x4;
typedef unsigned short u16;

__device__ __forceinline__ u16 f2bf(float f) {
    union { float f; unsigned u; } v; v.f = f;
    unsigned u = v.u;
    return (u16)((u + 0x7fffu + ((u >> 16) & 1u)) >> 16);
}
__device__ __forceinline__ float bf2f(u16 h) {
    union { unsigned u; float f; } v; v.u = ((unsigned)h) << 16; return v.f;
}
__device__ __forceinline__ float lodv(const float* p) { return *p; }
__device__ __forceinline__ float lodv(const u16* p) { return bf2f(*p); }
__device__ __forceinline__ void storv(float* p, float v) { *p = v; }
__device__ __forceinline__ void storv(u16* p, float v) { *p = f2bf(v); }

// Pre-swizzle weights into MFMA A-fragment order (bf16), K-order (kw outer, ci inner)
__global__ void prep_kernel(const float* __restrict__ wd, const float* __restrict__ wu,
                            const float* __restrict__ wr, const float* __restrict__ wl,
                            u16* __restrict__ afrag) {
    const int bid = blockIdx.x;             // p*288 + ct*36 + kk
    const int p = bid / (8 * NCHUNK);
    const int rem = bid % (8 * NCHUNK);
    const int ct = rem / NCHUNK;
    const int kk = rem % NCHUNK;
    const float* w = (p == 0) ? wd : (p == 1) ? wu : (p == 2) ? wr : wl;
    const int lane = threadIdx.x;
    const int co = ct * 16 + (lane & 15);
    const int k0 = kk * 32 + ((lane >> 4) << 3);
    u16 v[8];
#pragma unroll
    for (int j = 0; j < 8; ++j) {
        const int k = k0 + j;
        const int kw = k >> 7;
        const int ci = k & 127;
        v[j] = f2bf(w[(co * C_ + ci) * K_ + kw]);
    }
    u16* dst = afrag + ((size_t)(bid * 64 + lane)) * 8;
#pragma unroll
    for (int j = 0; j < 8; ++j) dst[j] = v[j];
}

// Within-pass step barrier: drain own LDS ops only; global stores stay in flight
__device__ __forceinline__ void step_barrier() {
    asm volatile("s_waitcnt lgkmcnt(0)\n\ts_barrier" ::: "memory");
}

// 4 waves; wave w computes co-tiles {2w, 2w+1} for ALL l. Each LDS B-fragment
// read feeds 2 MFMAs. areg1 + areg0[18..35] pinned to AGPRs -> no scratch.
// SKIP_T / STORE_T select normal [c][h][w] vs column-major [t][c][h] layouts.
template <int AXIS, bool SKIP_T, bool STORE_T, int NROWS, typename TF>
__device__ __forceinline__ void run_pass(
    const float* __restrict__ stbase,      // initial-carry source (normal layout)
    const float* __restrict__ sread,       // skip source (normal layout)
    float* __restrict__ fb,                // normal-layout output (STORE_T=false)
    TF* __restrict__ fbT,                  // column-major field (W passes)
    const u16* __restrict__ afr,           // this pass's swizzled weights
    const float* __restrict__ bias,
    const int nsteps, const int start, const int dir, const int stage_t,
    u16* __restrict__ lds)
{
    constexpr int L = (AXIS == 0) ? W_ : H_;
    constexpr int NLT = (AXIS == 0) ? 7 : 3;   // l-tiles of 16
    const int tid = threadIdx.x;
    const int lane = tid & 63;
    const int wv = tid >> 6;               // 0..3
    const int q = lane >> 4, r = lane & 15;
    const int ct0 = 2 * wv, ct1 = ct0 + 1;
    const int cob0 = ct0 * 16 + (q << 2);
    const int cob1 = ct1 * 16 + (q << 2);

    // ---- weights for this wave's 2 co-tiles; force AGPR residency ----
    short8 areg0[NCHUNK], areg1[NCHUNK];
    {
        const u16* ap0 = afr + ((size_t)(ct0 * NCHUNK) * 64 + lane) * 8;
        const u16* ap1 = afr + ((size_t)(ct1 * NCHUNK) * 64 + lane) * 8;
#pragma unroll
        for (int kk = 0; kk < NCHUNK; ++kk) {
            areg0[kk] = *(const short8*)(ap0 + (size_t)kk * 512);
            areg1[kk] = *(const short8*)(ap1 + (size_t)kk * 512);
            asm("" : "+a"(areg1[kk]));
            if (kk >= 18) asm("" : "+a"(areg0[kk]));
        }
    }
    float bias0[4], bias1[4];
#pragma unroll
    for (int j = 0; j < 4; ++j) { bias0[j] = bias[cob0 + j]; bias1[j] = bias[cob1 + j]; }

    // entry: full barrier (drains prior pass's global writes for cross-thread reads)
    __syncthreads();

    // ---- stage initial carry (full 128 ch) into buffer 0 ----
    for (int e = tid; e < C_ * L; e += 256) {
        const int c = e / L, l = e - c * L;
        float fv;
        if constexpr (SKIP_T)
            fv = lodv(&fbT[((size_t)stage_t * C_ + c) * H_ + l]);
        else
            fv = stbase[(AXIS == 0) ? (c * H_ + stage_t) * W_ + l
                                    : (c * H_ + l) * W_ + stage_t];
        lds[(l + PAD_) * LDSTRIDE + c] = f2bf(fv);
        if constexpr (STORE_T && !SKIP_T)   // publish carry col to fbT if absent
            storv(&fbT[((size_t)stage_t * C_ + c) * H_ + l], fv);
    }
    __syncthreads();

    for (int s = 1; s <= nsteps; ++s) {
        const int cur = (s - 1) & 1, nxt = s & 1;
        const int t = start + dir * s;
        const u16* curb = lds + (size_t)cur * NROWS * LDSTRIDE;
        u16* nxtb = lds + (size_t)nxt * NROWS * LDSTRIDE;

#pragma unroll
        for (int ltp = 0; ltp < NLT; ltp += 2) {
            const bool two = (ltp + 1 < NLT);
            const int lA = ltp * 16 + r;
            const int lB = lA + 16;
            const bool vA = (lA < L);
            const bool vB = two && (lB < L);

            auto ld_skip = [&](int co, int l) -> float {
                if constexpr (SKIP_T) {
                    return lodv(&fbT[((size_t)t * C_ + co) * H_ + l]);
                } else {
                    const int fi = (AXIS == 0) ? (co * H_ + t) * W_ + l
                                               : (co * H_ + l) * W_ + t;
                    return sread[fi];
                }
            };
            float svA0[4], svA1[4], svB0[4], svB1[4];
#pragma unroll
            for (int j = 0; j < 4; ++j) {
                svA0[j] = vA ? ld_skip(cob0 + j, lA) : 0.0f;
                svA1[j] = vA ? ld_skip(cob1 + j, lA) : 0.0f;
                if (two) {
                    svB0[j] = vB ? ld_skip(cob0 + j, lB) : 0.0f;
                    svB1[j] = vB ? ld_skip(cob1 + j, lB) : 0.0f;
                }
            }

            f32x4 aA0 = {bias0[0], bias0[1], bias0[2], bias0[3]};
            f32x4 aA1 = {bias1[0], bias1[1], bias1[2], bias1[3]};
            f32x4 aB0 = aA0;
            f32x4 aB1 = aA1;
#pragma unroll
            for (int kk = 0; kk < NCHUNK; ++kk) {
                const int kw = kk >> 2;
                const int cib = ((kk & 3) << 5) | (q << 3);
                const short8 bvA = *(const short8*)&curb[(lA + kw) * LDSTRIDE + cib];
                aA0 = __builtin_amdgcn_mfma_f32_16x16x32_bf16(areg0[kk], bvA, aA0, 0, 0, 0);
                aA1 = __builtin_amdgcn_mfma_f32_16x16x32_bf16(areg1[kk], bvA, aA1, 0, 0, 0);
                if (two) {
                    const short8 bvB = *(const short8*)&curb[(lB + kw) * LDSTRIDE + cib];
                    aB0 = __builtin_amdgcn_mfma_f32_16x16x32_bf16(areg0[kk], bvB, aB0, 0, 0, 0);
                    aB1 = __builtin_amdgcn_mfma_f32_16x16x32_bf16(areg1[kk], bvB, aB1, 0, 0, 0);
                }
            }

            auto epi = [&](int l, bool valid, const f32x4& a, const float* sv,
                           const int cob) {
                if (!valid) return;
                union { u16 s4[4]; unsigned long long v; } pk;
#pragma unroll
                for (int j = 0; j < 4; ++j) {
                    const float conv = fmaxf(a[j], 0.0f);   // bias already in acc
                    const float nv = sv[j] + conv;
                    if constexpr (STORE_T) {
                        storv(&fbT[((size_t)t * C_ + cob + j) * H_ + l], nv);
                    } else {
                        const int fi = (AXIS == 0) ? ((cob + j) * H_ + t) * W_ + l
                                                   : ((cob + j) * H_ + l) * W_ + t;
                        fb[fi] = nv;
                    }
                    pk.s4[j] = f2bf(nv);
                }
                *(unsigned long long*)&nxtb[(l + PAD_) * LDSTRIDE + cob] = pk.v;
            };
            epi(lA, vA, aA0, svA0, cob0);
            epi(lA, vA, aA1, svA1, cob1);
            if (two) {
                epi(lB, vB, aB0, svB0, cob0);
                epi(lB, vB, aB1, svB1, cob1);
            }
        }
        step_barrier();   // LDS-only drain; global stores keep flying
    }
}

__global__ __launch_bounds__(256, 1) void spatialH(
    const float* __restrict__ x, float* __restrict__ fb,
    const u16* __restrict__ afrag,
    const float* __restrict__ bd, const float* __restrict__ bu) {
    __shared__ __align__(16) u16 lds[2 * NR_H * LDSTRIDE];
    const int b = blockIdx.x;
    const int tid = threadIdx.x;
    const float* xb = x + (size_t)b * C_ * H_ * W_;
    float* fbb = fb + (size_t)b * C_ * H_ * W_;

    // field row h=0 (= x)
    for (int e = tid; e < C_ * W_; e += 256) {
        const int c = e / W_, w = e - c * W_;
        fbb[(c * H_) * W_ + w] = xb[(c * H_) * W_ + w];
    }
    // zero LDS (halo rows must be 0); ordered vs staging by run_pass entry sync
    for (int off = tid * 8; off < 2 * NR_H * LDSTRIDE; off += 256 * 8)
        *(uint4*)(&lds[off]) = make_uint4(0u, 0u, 0u, 0u);

    // down: h = 1..35 ; up: h = 34..1
    run_pass<0, false, false, NR_H, float>(xb, xb, fbb, (float*)nullptr,
        afrag + (size_t)0 * PASSSZ, bd, 35, 0, +1, 0, lds);
    run_pass<0, false, false, NR_H, float>(fbb, fbb, fbb, (float*)nullptr,
        afrag + (size_t)1 * PASSSZ, bu, 34, 35, -1, 35, lds);
}

// field[b][c][h][w] -> fbT[b][w][c][h], LDS-tiled, both sides coalesced
template <typename TF>
__global__ void t1_kernel(const float* __restrict__ in, TF* __restrict__ fbT) {
    __shared__ float tile[16 * 36 * 17];
    const int tid = threadIdx.x;
    const int bid = blockIdx.x;            // b*56 + cs*7 + wc
    const int b = bid / 56;
    const int rem = bid % 56;
    const int cs = rem / 7, wc = rem % 7;
    const int w0 = wc * 16;
    const int wlen = (w0 + 16 <= W_) ? 16 : (W_ - w0);
    const int c0 = cs * 16;
    const float* src = in + (size_t)b * C_ * H_ * W_;
    TF* dst = fbT + (size_t)b * W_ * C_ * H_;

    for (int j = tid; j < 576 * 16; j += 256) {
        const int w = j & 15;
        const int ch = j >> 4;
        if (w >= wlen) continue;
        const int c = ch / 36, h = ch - c * 36;
        tile[(c * 36 + h) * 17 + w] = src[((size_t)(c0 + c) * H_ + h) * W_ + w0 + w];
    }
    __syncthreads();
    for (int i = tid; i < 576 * wlen; i += 256) {
        const int w = i / 576;
        const int ch = i - w * 576;
        const int c = ch / 36, h = ch - c * 36;
        storv(&dst[((size_t)(w0 + w) * C_ + c0 + c) * H_ + h],
              tile[(c * 36 + h) * 17 + w]);
    }
}

template <typename TF>
__global__ __launch_bounds__(256, 1) void spatialW(
    TF* __restrict__ fbT, const u16* __restrict__ afrag,
    const float* __restrict__ br_, const float* __restrict__ bl_) {
    __shared__ __align__(16) u16 lds[2 * NR_W * LDSTRIDE];
    const int b = blockIdx.x;
    const int tid = threadIdx.x;
    TF* fbTb = fbT + (size_t)b * W_ * C_ * H_;

    for (int off = tid * 8; off < 2 * NR_W * LDSTRIDE; off += 256 * 8)
        *(uint4*)(&lds[off]) = make_uint4(0u, 0u, 0u, 0u);

    // right: w = 1..99 (skip+stage+stores all dense on fbT, in-place)
    run_pass<1, true, true, NR_W, TF>((const float*)nullptr, (const float*)nullptr,
        (float*)nullptr, fbTb, afrag + (size_t)2 * PASSSZ, br_, 99, 0, +1, 0, lds);
    // left: w = 98..1 (same)
    run_pass<1, true, true, NR_W, TF>((const float*)nullptr, (const float*)nullptr,
        (float*)nullptr, fbTb, afrag + (size_t)3 * PASSSZ, bl_, 98, 99, -1, 99, lds);
}

// fbT[b][w][c][h] -> out[b][c][h][w], LDS-tiled, both sides coalesced
template <typename TF>
__global__ void t2_kernel(const TF* __restrict__ fbT, float* __restrict__ out) {
    __shared__ float tile[16 * 36 * 17];
    const int tid = threadIdx.x;
    const int bid = blockIdx.x;            // b*56 + cs*7 + wc
    const int b = bid / 56;
    const int rem = bid % 56;
    const int cs = rem / 7, wc = rem % 7;
    const int w0 = wc * 16;
    const int wlen = (w0 + 16 <= W_) ? 16 : (W_ - w0);
    const int c0 = cs * 16;
    const TF* src = fbT + (size_t)b * W_ * C_ * H_;

    for (int i = tid; i < 576 * wlen; i += 256) {
        const int w = i / 576;
        const int ch = i - w * 576;
        const int c = ch / 36, h = ch - c * 36;
        tile[(c * 36 + h) * 17 + w] = lodv(&src[((size_t)(w0 + w) * C_ + c0 + c) * H_ + h]);
    }
    __syncthreads();
    for (int j = tid; j < 576 * 16; j += 256) {
        const int w = j & 15;
        const int ch = j >> 4;
        if (w >= wlen) continue;
        const int c = ch / 36, h = ch - c * 36;
        out[(((size_t)b * C_ + c0 + c) * H_ + h) * W_ + w0 + w] = tile[(c * 36 + h) * 17 + w];
    }
}

extern "C" void kernel_launch(void* const* d_in, const int* in_sizes, int n_in,
                              void* d_out, int out_size, void* d_ws, size_t ws_size,
                              hipStream_t stream) {
    const float* x  = (const float*)d_in[0];
    const float* wd = (const float*)d_in[1];
    const float* bd = (const float*)d_in[2];
    const float* wu = (const float*)d_in[3];
    const float* bu = (const float*)d_in[4];
    const float* wr = (const float*)d_in[5];
    const float* br = (const float*)d_in[6];
    const float* wl = (const float*)d_in[7];
    const float* bl = (const float*)d_in[8];

    // ws layout: [0,1KB) unused | afrag (2.36 MB) | pad | fbT @ 4MB (118/59 MB)
    u16* afrag = (u16*)((char*)d_ws + 1024);
    void* fbTp = (char*)d_ws + FBT_OFF;
    const bool f32ok = ws_size >= FBT_OFF + sizeof(float) * FBT_ELEMS;

    prep_kernel<<<dim3(4 * 8 * NCHUNK), dim3(64), 0, stream>>>(wd, wu, wr, wl, afrag);
    spatialH<<<dim3(64), dim3(256), 0, stream>>>(x, (float*)d_out, afrag, bd, bu);
    if (f32ok) {
        t1_kernel<float><<<dim3(64 * 56), dim3(256), 0, stream>>>(
            (const float*)d_out, (float*)fbTp);
        spatialW<float><<<dim3(64), dim3(256), 0, stream>>>(
            (float*)fbTp, afrag, br, bl);
        t2_kernel<float><<<dim3(64 * 56), dim3(256), 0, stream>>>(
            (const float*)fbTp, (float*)d_out);
    } else {
        t1_kernel<u16><<<dim3(64 * 56), dim3(256), 0, stream>>>(
            (const float*)d_out, (u16*)fbTp);
        spatialW<u16><<<dim3(64), dim3(256), 0, stream>>>(
            (u16*)fbTp, afrag, br, bl);
        t2_kernel<u16><<<dim3(64 * 56), dim3(256), 0, stream>>>(
            (const u16*)fbTp, (float*)d_out);
    }
}